// Round 2
// baseline (2327.089 us; speedup 1.0000x reference)
//
#include <hip/hip_runtime.h>
#include <math.h>

#define EPS 1e-8f
#define NXCD 8

// Read the hardware XCC (XCD) id — wave-uniform, 0..7 on MI355X.
__device__ __forceinline__ unsigned xcc_id() {
    unsigned x;
    asm volatile("s_getreg_b32 %0, hwreg(HW_REG_XCC_ID)" : "=s"(x));
    return x & (NXCD - 1);
}

// ---------------------------------------------------------------------------
// Pass 1 (privatized): per-edge outer products scattered into the XCD-local
// copy of S using WORKGROUP-scope atomics. These execute in the local L2
// (no sc1 bit -> no per-atomic 32B HBM transaction). Cross-XCD visibility is
// provided by the implicit end-of-dispatch release (dirty L2 write-back).
// ---------------------------------------------------------------------------
__global__ __launch_bounds__(256) void edge_pass1_priv(
    const float* __restrict__ mu0, const float* __restrict__ mu,
    const int* __restrict__ ei, const int* __restrict__ ej,
    float* __restrict__ S, double* __restrict__ sums, int E, int N)
{
    int tid = blockIdx.x * blockDim.x + threadIdx.x;
    unsigned xcc = xcc_id();
    float* Sx = S + (size_t)xcc * N * 9;
    double wv = 0.0;
    if (tid < E) {
        int i = ei[tid];
        int j = ej[tid];
        float a0 = mu0[3*i+0], a1 = mu0[3*i+1], a2 = mu0[3*i+2];
        float b0 = mu0[3*j+0], b1 = mu0[3*j+1], b2 = mu0[3*j+2];
        float r0 = b0 - a0, r1 = b1 - a1, r2 = b2 - a2;
        float c0 = mu[3*i+0], c1 = mu[3*i+1], c2 = mu[3*i+2];
        float e0 = mu[3*j+0], e1 = mu[3*j+1], e2 = mu[3*j+2];
        float d0 = e0 - c0, d1 = e1 - c1, d2 = e2 - c2;
        float w = 1.0f / (sqrtf(r0*r0 + r1*r1 + r2*r2) + EPS);
        wv = (double)w;
        float* Si = Sx + (size_t)9 * i;
        float wd0 = w * d0, wd1 = w * d1, wd2 = w * d2;
        __hip_atomic_fetch_add(Si + 0, wd0 * r0, __ATOMIC_RELAXED, __HIP_MEMORY_SCOPE_WORKGROUP);
        __hip_atomic_fetch_add(Si + 1, wd0 * r1, __ATOMIC_RELAXED, __HIP_MEMORY_SCOPE_WORKGROUP);
        __hip_atomic_fetch_add(Si + 2, wd0 * r2, __ATOMIC_RELAXED, __HIP_MEMORY_SCOPE_WORKGROUP);
        __hip_atomic_fetch_add(Si + 3, wd1 * r0, __ATOMIC_RELAXED, __HIP_MEMORY_SCOPE_WORKGROUP);
        __hip_atomic_fetch_add(Si + 4, wd1 * r1, __ATOMIC_RELAXED, __HIP_MEMORY_SCOPE_WORKGROUP);
        __hip_atomic_fetch_add(Si + 5, wd1 * r2, __ATOMIC_RELAXED, __HIP_MEMORY_SCOPE_WORKGROUP);
        __hip_atomic_fetch_add(Si + 6, wd2 * r0, __ATOMIC_RELAXED, __HIP_MEMORY_SCOPE_WORKGROUP);
        __hip_atomic_fetch_add(Si + 7, wd2 * r1, __ATOMIC_RELAXED, __HIP_MEMORY_SCOPE_WORKGROUP);
        __hip_atomic_fetch_add(Si + 8, wd2 * r2, __ATOMIC_RELAXED, __HIP_MEMORY_SCOPE_WORKGROUP);
    }
    // wave-64 reduction of w into device-scope double accumulator
    #pragma unroll
    for (int off = 32; off > 0; off >>= 1)
        wv += __shfl_down(wv, off);
    if ((threadIdx.x & 63) == 0)
        atomicAdd(sums + 0, wv);
}

// Fallback (device-scope atomics, single copy) if ws_size is too small.
__global__ __launch_bounds__(256) void edge_pass1_dev(
    const float* __restrict__ mu0, const float* __restrict__ mu,
    const int* __restrict__ ei, const int* __restrict__ ej,
    float* __restrict__ S, double* __restrict__ sums, int E)
{
    int tid = blockIdx.x * blockDim.x + threadIdx.x;
    double wv = 0.0;
    if (tid < E) {
        int i = ei[tid];
        int j = ej[tid];
        float a0 = mu0[3*i+0], a1 = mu0[3*i+1], a2 = mu0[3*i+2];
        float b0 = mu0[3*j+0], b1 = mu0[3*j+1], b2 = mu0[3*j+2];
        float r0 = b0 - a0, r1 = b1 - a1, r2 = b2 - a2;
        float c0 = mu[3*i+0], c1 = mu[3*i+1], c2 = mu[3*i+2];
        float e0 = mu[3*j+0], e1 = mu[3*j+1], e2 = mu[3*j+2];
        float d0 = e0 - c0, d1 = e1 - c1, d2 = e2 - c2;
        float w = 1.0f / (sqrtf(r0*r0 + r1*r1 + r2*r2) + EPS);
        wv = (double)w;
        float* Si = S + (size_t)9 * i;
        float wd0 = w * d0, wd1 = w * d1, wd2 = w * d2;
        atomicAdd(Si + 0, wd0 * r0); atomicAdd(Si + 1, wd0 * r1); atomicAdd(Si + 2, wd0 * r2);
        atomicAdd(Si + 3, wd1 * r0); atomicAdd(Si + 4, wd1 * r1); atomicAdd(Si + 5, wd1 * r2);
        atomicAdd(Si + 6, wd2 * r0); atomicAdd(Si + 7, wd2 * r1); atomicAdd(Si + 8, wd2 * r2);
    }
    #pragma unroll
    for (int off = 32; off > 0; off >>= 1)
        wv += __shfl_down(wv, off);
    if ((threadIdx.x & 63) == 0)
        atomicAdd(sums + 0, wv);
}

// ---------------------------------------------------------------------------
// Pass 2: sum the per-XCD copies, then nearest rotation via scaled Newton
// polar iteration. Replicates the reference det-fix (negate FIRST column).
// ---------------------------------------------------------------------------
__global__ __launch_bounds__(256) void node_pass(
    const float* __restrict__ S, float* __restrict__ R, int N, int ncopy)
{
    int n = blockIdx.x * blockDim.x + threadIdx.x;
    if (n >= N) return;
    float X[9] = {0.f,0.f,0.f,0.f,0.f,0.f,0.f,0.f,0.f};
    for (int c = 0; c < ncopy; ++c) {
        const float* Sc = S + ((size_t)c * N + n) * 9;
        #pragma unroll
        for (int k = 0; k < 9; ++k) X[k] += Sc[k];
    }

    bool ok = true;
    #pragma unroll
    for (int it = 0; it < 8; ++it) {
        float c00 =  (X[4]*X[8] - X[5]*X[7]);
        float c01 = -(X[3]*X[8] - X[5]*X[6]);
        float c02 =  (X[3]*X[7] - X[4]*X[6]);
        float c10 = -(X[1]*X[8] - X[2]*X[7]);
        float c11 =  (X[0]*X[8] - X[2]*X[6]);
        float c12 = -(X[0]*X[7] - X[1]*X[6]);
        float c20 =  (X[1]*X[5] - X[2]*X[4]);
        float c21 = -(X[0]*X[5] - X[2]*X[3]);
        float c22 =  (X[0]*X[4] - X[1]*X[3]);
        float det = X[0]*c00 + X[1]*c01 + X[2]*c02;
        if (!(fabsf(det) > 1e-30f)) { ok = false; break; }
        float inv_det = 1.0f / det;
        float Y[9] = { c00*inv_det, c01*inv_det, c02*inv_det,
                       c10*inv_det, c11*inv_det, c12*inv_det,
                       c20*inv_det, c21*inv_det, c22*inv_det };
        float nx = 0.f, ny = 0.f;
        #pragma unroll
        for (int k = 0; k < 9; ++k) { nx += X[k]*X[k]; ny += Y[k]*Y[k]; }
        float g = sqrtf(sqrtf(ny / nx));
        float hg = 0.5f * g, hig = 0.5f / g;
        #pragma unroll
        for (int k = 0; k < 9; ++k) X[k] = hg * X[k] + hig * Y[k];
    }
    if (!ok) {
        X[0] = 1.f; X[1] = 0.f; X[2] = 0.f;
        X[3] = 0.f; X[4] = 1.f; X[5] = 0.f;
        X[6] = 0.f; X[7] = 0.f; X[8] = 1.f;
    }
    float det = X[0]*(X[4]*X[8] - X[5]*X[7])
              - X[1]*(X[3]*X[8] - X[5]*X[6])
              + X[2]*(X[3]*X[7] - X[4]*X[6]);
    if (det < 0.f) { X[0] = -X[0]; X[3] = -X[3]; X[6] = -X[6]; }
    #pragma unroll
    for (int k = 0; k < 9; ++k) R[(size_t)9 * n + k] = X[k];
}

// ---------------------------------------------------------------------------
// Pass 3: per-edge residual, accumulate sum(w * ||deform - R_i rest||^2).
// ---------------------------------------------------------------------------
__global__ __launch_bounds__(256) void edge_pass2(
    const float* __restrict__ mu0, const float* __restrict__ mu,
    const int* __restrict__ ei, const int* __restrict__ ej,
    const float* __restrict__ R, double* __restrict__ sums, int E)
{
    int tid = blockIdx.x * blockDim.x + threadIdx.x;
    double cv = 0.0;
    if (tid < E) {
        int i = ei[tid];
        int j = ej[tid];
        float a0 = mu0[3*i+0], a1 = mu0[3*i+1], a2 = mu0[3*i+2];
        float b0 = mu0[3*j+0], b1 = mu0[3*j+1], b2 = mu0[3*j+2];
        float r0 = b0 - a0, r1 = b1 - a1, r2 = b2 - a2;
        float c0 = mu[3*i+0], c1 = mu[3*i+1], c2 = mu[3*i+2];
        float e0 = mu[3*j+0], e1 = mu[3*j+1], e2 = mu[3*j+2];
        float d0 = e0 - c0, d1 = e1 - c1, d2 = e2 - c2;
        float w = 1.0f / (sqrtf(r0*r0 + r1*r1 + r2*r2) + EPS);
        const float* Ri = R + (size_t)9 * i;
        float p0 = Ri[0]*r0 + Ri[1]*r1 + Ri[2]*r2;
        float p1 = Ri[3]*r0 + Ri[4]*r1 + Ri[5]*r2;
        float p2 = Ri[6]*r0 + Ri[7]*r1 + Ri[8]*r2;
        float x0 = d0 - p0, x1 = d1 - p1, x2 = d2 - p2;
        cv = (double)(w * (x0*x0 + x1*x1 + x2*x2));
    }
    #pragma unroll
    for (int off = 32; off > 0; off >>= 1)
        cv += __shfl_down(cv, off);
    if ((threadIdx.x & 63) == 0)
        atomicAdd(sums + 1, cv);
}

__global__ void finalize(const double* __restrict__ sums, float* __restrict__ out)
{
    out[0] = (float)(0.01 * (sums[1] / sums[0]));
}

extern "C" void kernel_launch(void* const* d_in, const int* in_sizes, int n_in,
                              void* d_out, int out_size, void* d_ws, size_t ws_size,
                              hipStream_t stream) {
    const float* mu0 = (const float*)d_in[0];
    const float* mu  = (const float*)d_in[1];
    const int*   eidx = (const int*)d_in[2];
    int N = in_sizes[0] / 3;
    int E = in_sizes[2] / 2;
    const int* ei = eidx;
    const int* ej = eidx + E;

    // workspace layout: [0,16): double sums[2]; [16,...): S copies; then R
    size_t s_elems_1 = (size_t)N * 9;
    size_t need_priv = 16 + (NXCD * s_elems_1 + s_elems_1) * sizeof(float);
    int ncopy = (ws_size >= need_priv) ? NXCD : 1;

    double* sums = (double*)d_ws;
    float*  S    = (float*)((char*)d_ws + 16);
    float*  R    = S + (size_t)ncopy * s_elems_1;

    hipMemsetAsync(d_ws, 0, 16 + (size_t)ncopy * s_elems_1 * sizeof(float), stream);

    int eb = (E + 255) / 256;
    int nb = (N + 255) / 256;
    if (ncopy == NXCD)
        edge_pass1_priv<<<eb, 256, 0, stream>>>(mu0, mu, ei, ej, S, sums, E, N);
    else
        edge_pass1_dev <<<eb, 256, 0, stream>>>(mu0, mu, ei, ej, S, sums, E);
    node_pass <<<nb, 256, 0, stream>>>(S, R, N, ncopy);
    edge_pass2<<<eb, 256, 0, stream>>>(mu0, mu, ei, ej, R, sums, E);
    finalize  <<<1, 1, 0, stream>>>(sums, (float*)d_out);
}

// Round 3
// 557.213 us; speedup vs baseline: 4.1763x; 4.1763x over previous
//
#include <hip/hip_runtime.h>
#include <math.h>

#define EPS 1e-8f

// ---------------------------------------------------------------------------
// K1: histogram of edge source nodes (int atomics).
// ---------------------------------------------------------------------------
__global__ __launch_bounds__(256) void k_count(
    const int* __restrict__ ei, int* __restrict__ cnt, int E)
{
    int t = blockIdx.x * blockDim.x + threadIdx.x;
    if (t < E) atomicAdd(cnt + ei[t], 1);
}

// ---------------------------------------------------------------------------
// K2a: per-block inclusive scan of cnt -> tmp, block totals -> bsum.
// ---------------------------------------------------------------------------
__global__ __launch_bounds__(256) void k_scan_local(
    const int* __restrict__ cnt, int* __restrict__ tmp,
    int* __restrict__ bsum, int N)
{
    __shared__ int sd[256];
    int t = threadIdx.x;
    int n = blockIdx.x * 256 + t;
    int x = (n < N) ? cnt[n] : 0;
    sd[t] = x;
    __syncthreads();
    for (int off = 1; off < 256; off <<= 1) {
        int v = (t >= off) ? sd[t - off] : 0;
        __syncthreads();
        sd[t] += v;
        __syncthreads();
    }
    if (n < N) tmp[n] = sd[t];
    if (t == 255) bsum[blockIdx.x] = sd[255];
}

// ---------------------------------------------------------------------------
// K2b: single-block exclusive scan of the block sums (NB <= 512).
// ---------------------------------------------------------------------------
__global__ __launch_bounds__(512) void k_scan_bsum(
    const int* __restrict__ bsum, int* __restrict__ bofs, int NB)
{
    __shared__ int sd[512];
    int t = threadIdx.x;
    int x = (t < NB) ? bsum[t] : 0;
    sd[t] = x;
    __syncthreads();
    for (int off = 1; off < 512; off <<= 1) {
        int v = (t >= off) ? sd[t - off] : 0;
        __syncthreads();
        sd[t] += v;
        __syncthreads();
    }
    if (t < NB) bofs[t] = sd[t] - x;   // exclusive
}

// ---------------------------------------------------------------------------
// K2c: global exclusive offsets -> start[] and cursor[]; start[N] = E.
// ---------------------------------------------------------------------------
__global__ __launch_bounds__(256) void k_finish_scan(
    const int* __restrict__ tmp, const int* __restrict__ cnt,
    const int* __restrict__ bofs, int* __restrict__ start,
    int* __restrict__ cursor, int N, int E)
{
    int n = blockIdx.x * blockDim.x + threadIdx.x;
    if (n < N) {
        int s = bofs[n >> 8] + tmp[n] - cnt[n];
        start[n] = s;
        cursor[n] = s;
    }
    if (n == 0) start[N] = E;
}

// ---------------------------------------------------------------------------
// K3: scatter target node j of each edge into the source node's bucket.
// ---------------------------------------------------------------------------
__global__ __launch_bounds__(256) void k_scatter(
    const int* __restrict__ ei, const int* __restrict__ ej,
    int* __restrict__ cursor, int* __restrict__ bucket, int E)
{
    int t = blockIdx.x * blockDim.x + threadIdx.x;
    if (t < E) {
        int pos = atomicAdd(cursor + ei[t], 1);
        bucket[pos] = ej[t];
    }
}

// ---------------------------------------------------------------------------
// K4: per-node: accumulate S in registers, polar-decompose, and use the
// trace identity  sum_e w||d - R r||^2 = sum_e w(||d||^2+||r||^2) - 2<R,S>_F
// (valid because R is orthogonal; the det-fix column negation keeps it so).
// No R storage, no second edge pass.
// ---------------------------------------------------------------------------
__global__ __launch_bounds__(256) void k_node(
    const float* __restrict__ mu0, const float* __restrict__ mu,
    const int* __restrict__ start, const int* __restrict__ bucket,
    double* __restrict__ sums, int N)
{
    int n = blockIdx.x * blockDim.x + threadIdx.x;
    double wsum = 0.0, errsum = 0.0;
    if (n < N) {
        float ax = mu0[3*n+0], ay = mu0[3*n+1], az = mu0[3*n+2];
        float cx = mu [3*n+0], cy = mu [3*n+1], cz = mu [3*n+2];
        float S[9] = {0.f,0.f,0.f,0.f,0.f,0.f,0.f,0.f,0.f};
        int beg = start[n], end = start[n+1];
        for (int p = beg; p < end; ++p) {
            int j = bucket[p];
            float bx = mu0[3*j+0], by = mu0[3*j+1], bz = mu0[3*j+2];
            float ex = mu [3*j+0], ey = mu [3*j+1], ez = mu [3*j+2];
            float r0 = bx - ax, r1 = by - ay, r2 = bz - az;
            float d0 = ex - cx, d1 = ey - cy, d2 = ez - cz;
            float rr = r0*r0 + r1*r1 + r2*r2;
            float dd = d0*d0 + d1*d1 + d2*d2;
            float w  = 1.0f / (sqrtf(rr) + EPS);
            wsum   += (double)w;
            errsum += (double)(w * (dd + rr));
            float wd0 = w*d0, wd1 = w*d1, wd2 = w*d2;
            S[0] += wd0*r0; S[1] += wd0*r1; S[2] += wd0*r2;
            S[3] += wd1*r0; S[4] += wd1*r1; S[5] += wd1*r2;
            S[6] += wd2*r0; S[7] += wd2*r1; S[8] += wd2*r2;
        }
        // scaled Newton polar iteration -> orthogonal factor of S
        float X[9];
        #pragma unroll
        for (int k = 0; k < 9; ++k) X[k] = S[k];
        bool ok = true;
        #pragma unroll
        for (int it = 0; it < 8; ++it) {
            float c00 =  (X[4]*X[8] - X[5]*X[7]);
            float c01 = -(X[3]*X[8] - X[5]*X[6]);
            float c02 =  (X[3]*X[7] - X[4]*X[6]);
            float c10 = -(X[1]*X[8] - X[2]*X[7]);
            float c11 =  (X[0]*X[8] - X[2]*X[6]);
            float c12 = -(X[0]*X[7] - X[1]*X[6]);
            float c20 =  (X[1]*X[5] - X[2]*X[4]);
            float c21 = -(X[0]*X[5] - X[2]*X[3]);
            float c22 =  (X[0]*X[4] - X[1]*X[3]);
            float det = X[0]*c00 + X[1]*c01 + X[2]*c02;
            if (!(fabsf(det) > 1e-30f)) { ok = false; break; }
            float inv_det = 1.0f / det;
            float Y[9] = { c00*inv_det, c01*inv_det, c02*inv_det,
                           c10*inv_det, c11*inv_det, c12*inv_det,
                           c20*inv_det, c21*inv_det, c22*inv_det };
            float nx = 0.f, ny = 0.f;
            #pragma unroll
            for (int k = 0; k < 9; ++k) { nx += X[k]*X[k]; ny += Y[k]*Y[k]; }
            float g = sqrtf(sqrtf(ny / nx));
            float hg = 0.5f * g, hig = 0.5f / g;
            #pragma unroll
            for (int k = 0; k < 9; ++k) X[k] = hg * X[k] + hig * Y[k];
        }
        if (!ok) {
            X[0]=1.f; X[1]=0.f; X[2]=0.f;
            X[3]=0.f; X[4]=1.f; X[5]=0.f;
            X[6]=0.f; X[7]=0.f; X[8]=1.f;
        }
        // reference det-fix quirk: det<0 -> negate FIRST column
        float det = X[0]*(X[4]*X[8] - X[5]*X[7])
                  - X[1]*(X[3]*X[8] - X[5]*X[6])
                  + X[2]*(X[3]*X[7] - X[4]*X[6]);
        if (det < 0.f) { X[0] = -X[0]; X[3] = -X[3]; X[6] = -X[6]; }
        // <R, S>_F
        float tr = X[0]*S[0] + X[1]*S[1] + X[2]*S[2]
                 + X[3]*S[3] + X[4]*S[4] + X[5]*S[5]
                 + X[6]*S[6] + X[7]*S[7] + X[8]*S[8];
        errsum -= 2.0 * (double)tr;
    }
    // wave-64 reduction, then one device atomic per wave per sum
    #pragma unroll
    for (int off = 32; off > 0; off >>= 1) {
        wsum   += __shfl_down(wsum, off);
        errsum += __shfl_down(errsum, off);
    }
    if ((threadIdx.x & 63) == 0) {
        atomicAdd(sums + 0, wsum);
        atomicAdd(sums + 1, errsum);
    }
}

__global__ void finalize(const double* __restrict__ sums, float* __restrict__ out)
{
    out[0] = (float)(0.01 * (sums[1] / sums[0]));
}

extern "C" void kernel_launch(void* const* d_in, const int* in_sizes, int n_in,
                              void* d_out, int out_size, void* d_ws, size_t ws_size,
                              hipStream_t stream) {
    const float* mu0 = (const float*)d_in[0];
    const float* mu  = (const float*)d_in[1];
    const int*   eidx = (const int*)d_in[2];
    int N = in_sizes[0] / 3;
    int E = in_sizes[2] / 2;
    const int* ei = eidx;
    const int* ej = eidx + E;

    int NB = (N + 255) / 256;   // 391 for N=100000; k_scan_bsum handles <=512

    // workspace layout (all 4-byte aligned):
    // [0,16) sums (2 doubles) | cnt N | tmp N | start N+1 | cursor N |
    // bsum NB | bofs NB | bucket E
    char* base = (char*)d_ws;
    double* sums = (double*)base;
    int* cnt    = (int*)(base + 16);
    int* tmp    = cnt + N;
    int* start  = tmp + N;
    int* cursor = start + (N + 1);
    int* bsum   = cursor + N;
    int* bofs   = bsum + NB;
    int* bucket = bofs + NB;

    // zero sums + cnt (workspace is poisoned with 0xAA before every call)
    hipMemsetAsync(d_ws, 0, 16 + (size_t)N * sizeof(int), stream);

    int eb = (E + 255) / 256;
    int nb = NB;
    k_count      <<<eb, 256, 0, stream>>>(ei, cnt, E);
    k_scan_local <<<nb, 256, 0, stream>>>(cnt, tmp, bsum, N);
    k_scan_bsum  <<<1, 512, 0, stream>>>(bsum, bofs, NB);
    k_finish_scan<<<nb, 256, 0, stream>>>(tmp, cnt, bofs, start, cursor, N, E);
    k_scatter    <<<eb, 256, 0, stream>>>(ei, ej, cursor, bucket, E);
    k_node       <<<nb, 256, 0, stream>>>(mu0, mu, start, bucket, sums, N);
    finalize     <<<1, 1, 0, stream>>>(sums, (float*)d_out);
}